// Round 5
// baseline (198.759 us; speedup 1.0000x reference)
//
#include <hip/hip_runtime.h>
#include <hip/hip_bf16.h>

// GraphAttentionLayer fused kernel for MI355X (gfx950).
// N=8192, IN=512, OUT=64. adj read (256MB @ ~6.9TB/s achievable => ~39us floor).
// K-A: Wh = h@W (fp32), Wh1L/W2L rank-1 score vectors (log2-scaled),
//      WhbT bf16 [64][8192], global max of W2L via orderable-uint atomicMax.
// K-B: fused mask+softmax+PV, FIXED per-row max bound (no online rescale),
//      8 waves/block. launch_bounds(512,3): (512,4) forced VGPR<=128 -> spills
//      in the hot loop (r3 regression 147->197us). Registers trimmed: depth-1
//      adj prefetch into same regs, B-fragment loaded just before its MFMA.
// (Resubmission of round-4 kernel — container died before measurement.)

#define LOG2E 1.4426950408889634f

typedef __attribute__((ext_vector_type(8))) short  short8v;
typedef __attribute__((ext_vector_type(4))) float  f32x4;

__device__ __forceinline__ unsigned short f2bf(float f) {
    union { float f; unsigned int u; } x; x.f = f;
    unsigned int r = x.u + 0x7FFFu + ((x.u >> 16) & 1u);   // RNE
    return (unsigned short)(r >> 16);
}

__device__ __forceinline__ unsigned fkey(float f) {       // order-preserving float->uint
    unsigned u = __float_as_uint(f);
    return (u & 0x80000000u) ? ~u : (u | 0x80000000u);
}
__device__ __forceinline__ float funkey(unsigned k) {
    return (k & 0x80000000u) ? __uint_as_float(k ^ 0x80000000u) : __uint_as_float(~k);
}

// ---------------- Kernel A: Wh, Wh1L, W2L, WhbT, gmax ----------------
// grid 1024 x 256. Each wave: 2 rows. 4096 waves -> 4 waves/SIMD.
__global__ __launch_bounds__(256) void wh_kernel(
        const float* __restrict__ h, const float* __restrict__ W,
        const float* __restrict__ a,
        unsigned short* __restrict__ WhbT,
        float* __restrict__ Wh1L, float* __restrict__ W2L,
        unsigned int* __restrict__ gkey) {
    const int wave = threadIdx.x >> 6;
    const int lane = threadIdx.x & 63;
    const int row0 = (blockIdx.x * 4 + wave) * 2;

    float acc0 = 0.f, acc1 = 0.f;
    const float* h0 = h + (size_t)row0 * 512;
    const float* h1 = h0 + 512;
    for (int i = 0; i < 512; i += 4) {
        float w0 = W[(i + 0) * 64 + lane];
        float w1 = W[(i + 1) * 64 + lane];
        float w2 = W[(i + 2) * 64 + lane];
        float w3 = W[(i + 3) * 64 + lane];
        float4 hv0 = *reinterpret_cast<const float4*>(h0 + i);
        float4 hv1 = *reinterpret_cast<const float4*>(h1 + i);
        acc0 = fmaf(hv0.x, w0, fmaf(hv0.y, w1, fmaf(hv0.z, w2, fmaf(hv0.w, w3, acc0))));
        acc1 = fmaf(hv1.x, w0, fmaf(hv1.y, w1, fmaf(hv1.z, w2, fmaf(hv1.w, w3, acc1))));
    }

    // bf16 transposed store (raw Wh values, used as MFMA B operand)
    ushort2 bt;
    bt.x = f2bf(acc0);
    bt.y = f2bf(acc1);
    *reinterpret_cast<ushort2*>(WhbT + (size_t)lane * 8192 + row0) = bt;

    // rank-1 score vectors, pre-scaled by log2(e)
    const float a1 = a[lane] * LOG2E, a2 = a[lane + 64] * LOG2E;
    float t10 = acc0 * a1, t20 = acc0 * a2;
    float t11 = acc1 * a1, t21 = acc1 * a2;
#pragma unroll
    for (int off = 32; off; off >>= 1) {
        t10 += __shfl_xor(t10, off);
        t20 += __shfl_xor(t20, off);
        t11 += __shfl_xor(t11, off);
        t21 += __shfl_xor(t21, off);
    }
    if (lane == 0) {
        Wh1L[row0] = t10; Wh1L[row0 + 1] = t11;
        W2L[row0]  = t20; W2L[row0 + 1]  = t21;
        atomicMax(gkey, fkey(fmaxf(t20, t21)));
    }
}

// ---------------- Kernel B: fused mask + softmax + PV ----------------
// grid 512 x 512 (8 waves). Block owns 16 rows; waves split j-range 8 ways.
// Fixed per-row max bound  mL = lrelu(wh1L + max_j w2L)  => p = 2^(s - mL) <= 1,
// masked entries p = 0. No online rescale; epilogue just sums l and acc.
__global__ __launch_bounds__(512, 3) void attn_kernel(
        const int* __restrict__ adj,
        const unsigned short* __restrict__ WhbT,
        const float* __restrict__ Wh1L, const float* __restrict__ W2L,
        const unsigned int* __restrict__ gkey,
        float* __restrict__ out) {
    __shared__ float sm_acc[8][64][17];   // padded: conflict-free epilogue reads
    __shared__ float sm_l[8][16];

    const int w    = threadIdx.x >> 6;
    const int lane = threadIdx.x & 63;
    const int r    = lane & 15;       // A-frag row / D col
    const int cg   = lane >> 4;       // k-chunk group
    const int i0   = blockIdx.x * 16;
    const int row  = i0 + r;

    const float wh1 = Wh1L[row];
    const float g2  = funkey(*gkey);
    const float mx  = wh1 + g2;
    const float mL  = mx > 0.f ? mx : 0.2f * mx;   // per-row upper bound (log2 domain)

    f32x4 acc[4];
#pragma unroll
    for (int f = 0; f < 4; ++f) acc[f] = (f32x4){0.f, 0.f, 0.f, 0.f};
    float lsum = 0.f;

    const int off0 = w * 32 + cg * 8;
    const int*            adjp = adj + (size_t)row * 8192 + off0;
    const float*          w2p  = W2L + off0;
    const unsigned short* bp   = WhbT + (size_t)r * 8192 + off0;

    int4 ac0 = *reinterpret_cast<const int4*>(adjp);
    int4 ac1 = *reinterpret_cast<const int4*>(adjp + 4);

    for (int it = 0; it < 32; ++it) {
        const int4 a0 = ac0, a1 = ac1;
        if (it < 31) {   // uniform branch; prefetch next adj pair
            ac0 = *reinterpret_cast<const int4*>(adjp + (it + 1) * 256);
            ac1 = *reinterpret_cast<const int4*>(adjp + (it + 1) * 256 + 4);
        }
        float4 w20 = *reinterpret_cast<const float4*>(w2p + it * 256);
        float4 w21 = *reinterpret_cast<const float4*>(w2p + it * 256 + 4);

        float p[8];
        {
            float t;
            t = wh1 + w20.x; t = t > 0.f ? t : 0.2f * t; p[0] = a0.x > 0 ? __builtin_exp2f(t - mL) : 0.f;
            t = wh1 + w20.y; t = t > 0.f ? t : 0.2f * t; p[1] = a0.y > 0 ? __builtin_exp2f(t - mL) : 0.f;
            t = wh1 + w20.z; t = t > 0.f ? t : 0.2f * t; p[2] = a0.z > 0 ? __builtin_exp2f(t - mL) : 0.f;
            t = wh1 + w20.w; t = t > 0.f ? t : 0.2f * t; p[3] = a0.w > 0 ? __builtin_exp2f(t - mL) : 0.f;
            t = wh1 + w21.x; t = t > 0.f ? t : 0.2f * t; p[4] = a1.x > 0 ? __builtin_exp2f(t - mL) : 0.f;
            t = wh1 + w21.y; t = t > 0.f ? t : 0.2f * t; p[5] = a1.y > 0 ? __builtin_exp2f(t - mL) : 0.f;
            t = wh1 + w21.z; t = t > 0.f ? t : 0.2f * t; p[6] = a1.z > 0 ? __builtin_exp2f(t - mL) : 0.f;
            t = wh1 + w21.w; t = t > 0.f ? t : 0.2f * t; p[7] = a1.w > 0 ? __builtin_exp2f(t - mL) : 0.f;
        }
        lsum += ((p[0] + p[1]) + (p[2] + p[3])) + ((p[4] + p[5]) + (p[6] + p[7]));

        short8v af;
#pragma unroll
        for (int b = 0; b < 8; ++b) af[b] = (short)f2bf(p[b]);

        const unsigned short* bpi = bp + it * 256;
#pragma unroll
        for (int f = 0; f < 4; ++f) {
            short8v bf = *reinterpret_cast<const short8v*>(bpi + (size_t)f * 16 * 8192);
            acc[f] = __builtin_amdgcn_mfma_f32_16x16x32_bf16(af, bf, acc[f], 0, 0, 0);
        }
    }

    // ---- combine across 8 waves (shared fixed m => plain sums) ----
    float ls = lsum;
    ls += __shfl_xor(ls, 16);
    ls += __shfl_xor(ls, 32);
    if (lane < 16) sm_l[w][lane] = ls;
#pragma unroll
    for (int f = 0; f < 4; ++f)
#pragma unroll
        for (int reg = 0; reg < 4; ++reg)
            sm_acc[w][lane][f * 4 + reg] = acc[f][reg];
    __syncthreads();

#pragma unroll
    for (int ss = 0; ss < 2; ++ss) {
        const int s = 2 * w + ss;
        const int f = s >> 2, reg = s & 3;
        float sum = 0.f;
#pragma unroll
        for (int ww = 0; ww < 8; ++ww) sum += sm_acc[ww][lane][s];
        const int R = 4 * cg + reg;
        float lrow = 0.f;
#pragma unroll
        for (int ww = 0; ww < 8; ++ww) lrow += sm_l[ww][R];
        float y = sum / lrow;
        y = y > 0.f ? y : expm1f(y);          // ELU, alpha=1
        out[(size_t)(i0 + R) * 64 + 16 * f + r] = y;
    }
}

extern "C" void kernel_launch(void* const* d_in, const int* in_sizes, int n_in,
                              void* d_out, int out_size, void* d_ws, size_t ws_size,
                              hipStream_t stream) {
    const float* h   = (const float*)d_in[0];
    const int*   adj = (const int*)d_in[1];
    const float* W   = (const float*)d_in[2];
    const float* a   = (const float*)d_in[3];

    unsigned short* WhbT = (unsigned short*)d_ws;                    // 1 MB
    float* Wh1L = (float*)((char*)d_ws + (1 << 20));                 // 32 KB
    float* W2L  = Wh1L + 8192;                                       // 32 KB
    unsigned int* gkey = (unsigned int*)(W2L + 8192);                // 4 B

    hipMemsetAsync(gkey, 0, 4, stream);                              // key 0 < any real key
    wh_kernel<<<1024, 256, 0, stream>>>(h, W, a, WhbT, Wh1L, W2L, gkey);
    attn_kernel<<<512, 512, 0, stream>>>(adj, WhbT, Wh1L, W2L, gkey, (float*)d_out);
}

// Round 6
// 170.273 us; speedup vs baseline: 1.1673x; 1.1673x over previous
//
#include <hip/hip_runtime.h>
#include <hip/hip_bf16.h>

// GraphAttentionLayer fused kernel for MI355X (gfx950).
// N=8192, IN=512, OUT=64. adj read (256MB @ ~6.9TB/s achievable => ~39us floor).
// K-A: Wh = h@W (fp32), Wh1L/W2L rank-1 score vectors (log2-scaled),
//      WhbT bf16 [64][8192]. NO atomics (r3/r5 single-address atomicMax from
//      4096 waves serialized at the coherence point: +50us tail -> removed).
// K-G: gmax_kernel (1 block) reduces max(W2L) -> scalar, replaces atomic+memset.
// K-B: fused mask+softmax+PV, FIXED per-row max bound (no online rescale),
//      8 waves/block, depth-1 adj register prefetch, mfma 16x16x32 bf16.

#define LOG2E 1.4426950408889634f

typedef __attribute__((ext_vector_type(8))) short  short8v;
typedef __attribute__((ext_vector_type(4))) float  f32x4;

__device__ __forceinline__ unsigned short f2bf(float f) {
    union { float f; unsigned int u; } x; x.f = f;
    unsigned int r = x.u + 0x7FFFu + ((x.u >> 16) & 1u);   // RNE
    return (unsigned short)(r >> 16);
}

// ---------------- Kernel A: Wh, Wh1L, W2L, WhbT ----------------
// grid 1024 x 256. Each wave: 2 rows. 4096 waves -> 4 waves/SIMD.
__global__ __launch_bounds__(256) void wh_kernel(
        const float* __restrict__ h, const float* __restrict__ W,
        const float* __restrict__ a,
        unsigned short* __restrict__ WhbT,
        float* __restrict__ Wh1L, float* __restrict__ W2L) {
    const int wave = threadIdx.x >> 6;
    const int lane = threadIdx.x & 63;
    const int row0 = (blockIdx.x * 4 + wave) * 2;

    float acc0 = 0.f, acc1 = 0.f;
    const float* h0 = h + (size_t)row0 * 512;
    const float* h1 = h0 + 512;
    for (int i = 0; i < 512; i += 4) {
        float w0 = W[(i + 0) * 64 + lane];
        float w1 = W[(i + 1) * 64 + lane];
        float w2 = W[(i + 2) * 64 + lane];
        float w3 = W[(i + 3) * 64 + lane];
        float4 hv0 = *reinterpret_cast<const float4*>(h0 + i);
        float4 hv1 = *reinterpret_cast<const float4*>(h1 + i);
        acc0 = fmaf(hv0.x, w0, fmaf(hv0.y, w1, fmaf(hv0.z, w2, fmaf(hv0.w, w3, acc0))));
        acc1 = fmaf(hv1.x, w0, fmaf(hv1.y, w1, fmaf(hv1.z, w2, fmaf(hv1.w, w3, acc1))));
    }

    // bf16 transposed store (raw Wh values, used as MFMA B operand)
    ushort2 bt;
    bt.x = f2bf(acc0);
    bt.y = f2bf(acc1);
    *reinterpret_cast<ushort2*>(WhbT + (size_t)lane * 8192 + row0) = bt;

    // rank-1 score vectors, pre-scaled by log2(e)
    const float a1 = a[lane] * LOG2E, a2 = a[lane + 64] * LOG2E;
    float t10 = acc0 * a1, t20 = acc0 * a2;
    float t11 = acc1 * a1, t21 = acc1 * a2;
#pragma unroll
    for (int off = 32; off; off >>= 1) {
        t10 += __shfl_xor(t10, off);
        t20 += __shfl_xor(t20, off);
        t11 += __shfl_xor(t11, off);
        t21 += __shfl_xor(t21, off);
    }
    if (lane == 0) {
        Wh1L[row0] = t10; Wh1L[row0 + 1] = t11;
        W2L[row0]  = t20; W2L[row0 + 1]  = t21;
    }
}

// ---------------- Kernel G: global max of W2L (replaces atomics) ----------------
__global__ __launch_bounds__(256) void gmax_kernel(
        const float* __restrict__ W2L, float* __restrict__ gmax) {
    __shared__ float sm[4];
    const int t = threadIdx.x;
    float m = -3.4e38f;
#pragma unroll
    for (int i = 0; i < 8; ++i) {
        float4 v = *reinterpret_cast<const float4*>(W2L + t * 4 + i * 1024);
        m = fmaxf(fmaxf(m, fmaxf(v.x, v.y)), fmaxf(v.z, v.w));
    }
#pragma unroll
    for (int off = 32; off; off >>= 1) m = fmaxf(m, __shfl_xor(m, off));
    if ((t & 63) == 0) sm[t >> 6] = m;
    __syncthreads();
    if (t == 0) *gmax = fmaxf(fmaxf(sm[0], sm[1]), fmaxf(sm[2], sm[3]));
}

// ---------------- Kernel B: fused mask + softmax + PV ----------------
// grid 512 x 512 (8 waves). Block owns 16 rows; waves split j-range 8 ways.
// Fixed per-row max bound  mL = lrelu(wh1L + max_j w2L)  => p = 2^(s - mL) <= 1,
// masked entries p = 0. No online rescale; epilogue just sums l and acc.
__global__ __launch_bounds__(512, 3) void attn_kernel(
        const int* __restrict__ adj,
        const unsigned short* __restrict__ WhbT,
        const float* __restrict__ Wh1L, const float* __restrict__ W2L,
        const float* __restrict__ gmaxp,
        float* __restrict__ out) {
    __shared__ float sm_acc[8][64][17];   // padded: conflict-free epilogue reads
    __shared__ float sm_l[8][16];

    const int w    = threadIdx.x >> 6;
    const int lane = threadIdx.x & 63;
    const int r    = lane & 15;       // A-frag row / D col
    const int cg   = lane >> 4;       // k-chunk group
    const int i0   = blockIdx.x * 16;
    const int row  = i0 + r;

    const float wh1 = Wh1L[row];
    const float g2  = *gmaxp;
    const float mx  = wh1 + g2;
    const float mL  = mx > 0.f ? mx : 0.2f * mx;   // per-row upper bound (log2 domain)

    f32x4 acc[4];
#pragma unroll
    for (int f = 0; f < 4; ++f) acc[f] = (f32x4){0.f, 0.f, 0.f, 0.f};
    float lsum = 0.f;

    const int off0 = w * 32 + cg * 8;
    const int*            adjp = adj + (size_t)row * 8192 + off0;
    const float*          w2p  = W2L + off0;
    const unsigned short* bp   = WhbT + (size_t)r * 8192 + off0;

    int4 ac0 = *reinterpret_cast<const int4*>(adjp);
    int4 ac1 = *reinterpret_cast<const int4*>(adjp + 4);

    for (int it = 0; it < 32; ++it) {
        const int4 a0 = ac0, a1 = ac1;
        if (it < 31) {   // uniform branch; prefetch next adj pair
            ac0 = *reinterpret_cast<const int4*>(adjp + (it + 1) * 256);
            ac1 = *reinterpret_cast<const int4*>(adjp + (it + 1) * 256 + 4);
        }
        float4 w20 = *reinterpret_cast<const float4*>(w2p + it * 256);
        float4 w21 = *reinterpret_cast<const float4*>(w2p + it * 256 + 4);

        float p[8];
        {
            float t;
            t = wh1 + w20.x; t = t > 0.f ? t : 0.2f * t; p[0] = a0.x > 0 ? __builtin_exp2f(t - mL) : 0.f;
            t = wh1 + w20.y; t = t > 0.f ? t : 0.2f * t; p[1] = a0.y > 0 ? __builtin_exp2f(t - mL) : 0.f;
            t = wh1 + w20.z; t = t > 0.f ? t : 0.2f * t; p[2] = a0.z > 0 ? __builtin_exp2f(t - mL) : 0.f;
            t = wh1 + w20.w; t = t > 0.f ? t : 0.2f * t; p[3] = a0.w > 0 ? __builtin_exp2f(t - mL) : 0.f;
            t = wh1 + w21.x; t = t > 0.f ? t : 0.2f * t; p[4] = a1.x > 0 ? __builtin_exp2f(t - mL) : 0.f;
            t = wh1 + w21.y; t = t > 0.f ? t : 0.2f * t; p[5] = a1.y > 0 ? __builtin_exp2f(t - mL) : 0.f;
            t = wh1 + w21.z; t = t > 0.f ? t : 0.2f * t; p[6] = a1.z > 0 ? __builtin_exp2f(t - mL) : 0.f;
            t = wh1 + w21.w; t = t > 0.f ? t : 0.2f * t; p[7] = a1.w > 0 ? __builtin_exp2f(t - mL) : 0.f;
        }
        lsum += ((p[0] + p[1]) + (p[2] + p[3])) + ((p[4] + p[5]) + (p[6] + p[7]));

        short8v af;
#pragma unroll
        for (int b = 0; b < 8; ++b) af[b] = (short)f2bf(p[b]);

        const unsigned short* bpi = bp + it * 256;
#pragma unroll
        for (int f = 0; f < 4; ++f) {
            short8v bf = *reinterpret_cast<const short8v*>(bpi + (size_t)f * 16 * 8192);
            acc[f] = __builtin_amdgcn_mfma_f32_16x16x32_bf16(af, bf, acc[f], 0, 0, 0);
        }
    }

    // ---- combine across 8 waves (shared fixed m => plain sums) ----
    float ls = lsum;
    ls += __shfl_xor(ls, 16);
    ls += __shfl_xor(ls, 32);
    if (lane < 16) sm_l[w][lane] = ls;
#pragma unroll
    for (int f = 0; f < 4; ++f)
#pragma unroll
        for (int reg = 0; reg < 4; ++reg)
            sm_acc[w][lane][f * 4 + reg] = acc[f][reg];
    __syncthreads();

#pragma unroll
    for (int ss = 0; ss < 2; ++ss) {
        const int s = 2 * w + ss;
        const int f = s >> 2, reg = s & 3;
        float sum = 0.f;
#pragma unroll
        for (int ww = 0; ww < 8; ++ww) sum += sm_acc[ww][lane][s];
        const int R = 4 * cg + reg;
        float lrow = 0.f;
#pragma unroll
        for (int ww = 0; ww < 8; ++ww) lrow += sm_l[ww][R];
        float y = sum / lrow;
        y = y > 0.f ? y : expm1f(y);          // ELU, alpha=1
        out[(size_t)(i0 + R) * 64 + 16 * f + r] = y;
    }
}

extern "C" void kernel_launch(void* const* d_in, const int* in_sizes, int n_in,
                              void* d_out, int out_size, void* d_ws, size_t ws_size,
                              hipStream_t stream) {
    const float* h   = (const float*)d_in[0];
    const int*   adj = (const int*)d_in[1];
    const float* W   = (const float*)d_in[2];
    const float* a   = (const float*)d_in[3];

    unsigned short* WhbT = (unsigned short*)d_ws;                    // 1 MB
    float* Wh1L = (float*)((char*)d_ws + (1 << 20));                 // 32 KB
    float* W2L  = Wh1L + 8192;                                       // 32 KB
    float* gmax = W2L + 8192;                                        // 4 B

    wh_kernel<<<1024, 256, 0, stream>>>(h, W, a, WhbT, Wh1L, W2L);
    gmax_kernel<<<1, 256, 0, stream>>>(W2L, gmax);
    attn_kernel<<<512, 512, 0, stream>>>(adj, WhbT, Wh1L, W2L, gmax, (float*)d_out);
}